// Round 14
// baseline (198.151 us; speedup 1.0000x reference)
//
#include <hip/hip_runtime.h>
#include <stdint.h>

// InstanceHead on MI355X — f32/int32 inputs, f32 OUTPUT buffer.
// N=100000, M=256, B=8, L=128, D=64.
// R19: isolate R18's two changes.  (a) GEMM1 operand swap (verified correct
// on HW) KEPT: mfma(wt,ff) -> lane (c,q) reg r = clu[c][nt*16+q*4+r];
// LDS transpose = 4x ds_write_b64 (pk_bf16 pairs) instead of 16x b16;
// norm reduce = 2 shuffles; bias via float4.  (b) cen_ws LDS staging
// REVERTED: it added a block-wide barrier that re-coupled the 4 waves into
// lockstep + drained the ff/wbv vmcnt queue (compiler emits vmcnt(0)
// before s_barrier) + 3x bank conflicts — profiled main regressed 70->86.
// Back to R14's global cenb with the 4-deep prefetch pipeline.
// Keeps R14: batched ff/wbv bursts, cmeta LDS (single top barrier),
// two-pass softmax, ep packed f16x2 in regs, transposed GEMM2 (row c,
// dwordx4 imm-offset stores), geometric batch fold (x+=4096*b; cross-batch
// exp -> exact 0; gate d2m<4e6), __launch_bounds__(256,3).

#define NN 100000
#define MM 256
#define LL 128
#define DD 64
#define NTILES (NN / 16)  // 6250, exact

typedef float f32x4 __attribute__((ext_vector_type(4)));
typedef __bf16 bf16x8 __attribute__((ext_vector_type(8)));
typedef __fp16 fp16x2 __attribute__((ext_vector_type(2)));

union U16x8 { uint4 u; bf16x8 v; unsigned short s[8]; };
union UH2 { unsigned int u; fp16x2 h; };

static __device__ __forceinline__ unsigned short f2bf(float f) {
  union { float f; unsigned int i; } t; t.f = f;
  unsigned int x = t.i;
  x += 0x7fffu + ((x >> 16) & 1u);  // round-to-nearest-even
  return (unsigned short)(x >> 16);
}

static __device__ __forceinline__ unsigned int pk_bf16(float lo, float hi) {
  unsigned int r;
  asm("v_cvt_pk_bf16_f32 %0, %1, %2" : "=v"(r) : "v"(lo), "v"(hi));
  return r;
}

// ---------------- prep: cen (bf16), W^T (bf16), centroid meta ----------------
__global__ __launch_bounds__(256) void prep_kernel(
    const int* __restrict__ cen_coords,
    const float* __restrict__ cen_feats,
    const float* __restrict__ conf,
    const float* __restrict__ W,
    const float* __restrict__ bvec,
    unsigned short* __restrict__ cen_ws,   // [256][64] bf16
    unsigned short* __restrict__ wt_ws,    // [64][128] bf16 (W transposed)
    float4* __restrict__ cmeta_ws)         // [256] {x+4096*batch, y, z, 0}
{
  int tid = threadIdx.x;
  if (blockIdx.x < 16) {
    int m = blockIdx.x * 16 + (tid >> 4);
    int c = tid & 15;
    float a0 = 0.f, a1 = 0.f, a2 = 0.f, a3 = 0.f;
    for (int l = 0; l < LL; l++) {
      float f = cen_feats[m * LL + l];
      const float* wr = W + l * DD + c;
      a0 += f * wr[0];  a1 += f * wr[16];
      a2 += f * wr[32]; a3 += f * wr[48];
    }
    float cf = conf[m];
    cen_ws[m * DD + c +  0] = f2bf(cf * (a0 + bvec[c +  0]));
    cen_ws[m * DD + c + 16] = f2bf(cf * (a1 + bvec[c + 16]));
    cen_ws[m * DD + c + 32] = f2bf(cf * (a2 + bvec[c + 32]));
    cen_ws[m * DD + c + 48] = f2bf(cf * (a3 + bvec[c + 48]));
  } else {
    for (int i = tid; i < LL * DD; i += 256) {
      int l = i >> 6, d = i & 63;
      wt_ws[d * LL + l] = f2bf(W[l * DD + d]);
    }
    {
      int4 cc = ((const int4*)cen_coords)[tid];  // {batch, x, y, z}
      float4 f;
      f.x = (float)cc.y + 4096.0f * (float)cc.x;  // batch folded into x
      f.y = (float)cc.z;
      f.z = (float)cc.w;
      f.w = 0.0f;
      cmeta_ws[tid] = f;
    }
  }
}

// ---------------- main: fused, 1 wave/tile ----------------
__global__ __launch_bounds__(256, 3) void main_kernel(
    const int4* __restrict__ clu_coords4,
    const float* __restrict__ feats,
    const float* __restrict__ bvec,
    const unsigned short* __restrict__ cen_ws,
    const unsigned short* __restrict__ wt_ws,
    const float4* __restrict__ cmeta,
    float* __restrict__ out)
{
  __shared__ __align__(16) unsigned short clu_s[4][16 * 72];  // wave-private
  __shared__ __align__(16) float4 cmeta_s[MM];                // block-shared

  int tid = threadIdx.x;
  cmeta_s[tid] = cmeta[tid];   // stage once per block
  __syncthreads();             // the only block barrier (before divergence)

  int wave = tid >> 6, lane = tid & 63;
  int q = lane >> 4, c = lane & 15;
  int tile = blockIdx.x * 4 + wave;
  if (tile >= NTILES) return;

  // ---- batched long-latency loads: feats (8x dwordx4), W frags (16x dwordx4),
  //      row coord — ALL issued before any dependent compute.
  const float4* fb = (const float4*)(feats + (size_t)(tile * 16 + c) * LL);
  float4 ff[8];
#pragma unroll
  for (int ks = 0; ks < 4; ks++) {
    ff[2 * ks]     = fb[ks * 8 + q * 2];
    ff[2 * ks + 1] = fb[ks * 8 + q * 2 + 1];
  }
  const uint4* wb = (const uint4*)wt_ws;
  uint4 wbv[16];
#pragma unroll
  for (int ks = 0; ks < 4; ks++)
#pragma unroll
    for (int nt = 0; nt < 4; nt++)
      wbv[ks * 4 + nt] = wb[(nt * 16 + c) * 16 + ks * 4 + q];
  int4 rm = clu_coords4[tile * 16 + c];            // one row per lane
  float rx = (float)rm.y + 4096.0f * (float)rm.x;  // batch folded, exact
  float ry = (float)rm.z;
  float rz = (float)rm.w;
  const float4* bv4 = (const float4*)bvec;
  float4 bb[4];
#pragma unroll
  for (int nt = 0; nt < 4; nt++) bb[nt] = bv4[nt * 4 + q];

  // ---- GEMM1 SWAPPED: acc[nt] lane (c,q) reg r = clu[i=c][d=nt*16+q*4+r]
  f32x4 acc[4] = {{0,0,0,0},{0,0,0,0},{0,0,0,0},{0,0,0,0}};
#pragma unroll
  for (int ks = 0; ks < 4; ks++) {
    float4 f0 = ff[2 * ks], f1 = ff[2 * ks + 1];
    U16x8 a;
    a.v[0] = (__bf16)f0.x; a.v[1] = (__bf16)f0.y; a.v[2] = (__bf16)f0.z; a.v[3] = (__bf16)f0.w;
    a.v[4] = (__bf16)f1.x; a.v[5] = (__bf16)f1.y; a.v[6] = (__bf16)f1.z; a.v[7] = (__bf16)f1.w;
#pragma unroll
    for (int nt = 0; nt < 4; nt++) {
      U16x8 b; b.u = wbv[ks * 4 + nt];
      acc[nt] = __builtin_amdgcn_mfma_f32_16x16x32_bf16(b.v, a.v, acc[nt], 0, 0, 0);  // SWAPPED
    }
  }
#pragma unroll
  for (int nt = 0; nt < 4; nt++) {
    acc[nt][0] += bb[nt][0]; acc[nt][1] += bb[nt][1];
    acc[nt][2] += bb[nt][2]; acc[nt][3] += bb[nt][3];
  }
  // ---- row norm: per-lane partial (16 d-values) + 2 shuffles over q-lanes
  float ns = 0.f;
#pragma unroll
  for (int nt = 0; nt < 4; nt++)
#pragma unroll
    for (int r = 0; r < 4; r++) ns += acc[nt][r] * acc[nt][r];
  ns += __shfl_xor(ns, 16);
  ns += __shfl_xor(ns, 32);
  float inv_nrm = 1.0f / fmaxf(sqrtf(ns), 1e-12f);

  // ---- normalized clu -> LDS: 4x ds_write_b64 (contiguous d per nt)
#pragma unroll
  for (int nt = 0; nt < 4; nt++) {
    uint2 w;
    w.x = pk_bf16(acc[nt][0] * inv_nrm, acc[nt][1] * inv_nrm);
    w.y = pk_bf16(acc[nt][2] * inv_nrm, acc[nt][3] * inv_nrm);
    *(uint2*)&clu_s[wave][c * 72 + nt * 16 + q * 4] = w;  // 8B-aligned
  }

  // wave-private LDS transpose: DS pipe is in-order per wave, no barrier
  __builtin_amdgcn_sched_barrier(0);

  // ---- clu frags (B-operand of the swapped GEMM2): row c, k-slice q
  const uint4* cb = (const uint4*)(clu_s[wave]);
  U16x8 a0, a1;
  a0.u = cb[c * 9 + q];       // k = q*8 .. q*8+7
  a1.u = cb[c * 9 + 4 + q];   // k = 32+q*8 ..

  // ---- issue the group-0 epilogue cen burst now; the passes below are
  //      DS/VALU-only, so these 8 dwordx4 stay in flight across them.
  const uint4* cenb = (const uint4*)cen_ws;
  uint4 pb0[4], pb1[4];
#pragma unroll
  for (int j = 0; j < 4; j++) {
    pb0[j] = cenb[(j * 16 + c) * 8 + q];
    pb1[j] = cenb[(j * 16 + c) * 8 + 4 + q];
  }

  // ---- pass 1: d^2 min for (row c, cols mt*16+q*4+r) — per-lane scalar
  float d2m = 1e30f;
#pragma unroll
  for (int mt = 0; mt < 16; mt++) {
#pragma unroll
    for (int r = 0; r < 4; r++) {
      float4 cm = cmeta_s[mt * 16 + q * 4 + r];
      float dx = rx - cm.x, dy = ry - cm.y, dz = rz - cm.z;
      d2m = fminf(d2m, dx * dx + dy * dy + dz * dz);
    }
  }
  d2m = fminf(d2m, __shfl_xor(d2m, 16));
  d2m = fminf(d2m, __shfl_xor(d2m, 32));
  float dmv = fmaxf(sqrtf(d2m), 0.1f);  // softmax reference (row min dist)

  // ---- pass 2: e = exp(dmin - d) once; pack f16x2 along r; row sum
  uint2 ep[16];
  float rsum = 0.f;
#pragma unroll
  for (int mt = 0; mt < 16; mt++) {
    float e[4];
#pragma unroll
    for (int r = 0; r < 4; r++) {
      float4 cm = cmeta_s[mt * 16 + q * 4 + r];
      float dx = rx - cm.x, dy = ry - cm.y, dz = rz - cm.z;
      float d = fmaxf(sqrtf(dx * dx + dy * dy + dz * dz), 0.1f);
      e[r] = __expf(dmv - d);  // <= 1; cross-batch -> exact 0
      rsum += e[r];
    }
    UH2 p0, p1;
    p0.h = __builtin_amdgcn_cvt_pkrtz(e[0], e[1]);
    p1.h = __builtin_amdgcn_cvt_pkrtz(e[2], e[3]);
    ep[mt].x = p0.u;
    ep[mt].y = p1.u;
  }
  rsum += __shfl_xor(rsum, 16);
  rsum += __shfl_xor(rsum, 32);
  // d2m >= 4e6 <=> no same-batch centroid -> exact-zero row
  float sc = (d2m < 4.0e6f) ? 1.0f / rsum : 0.f;

  // ---- epilogue: swapped GEMM2, 4-deep software-pipelined cen prefetch
  //      lane (c,q) reg r = out[row tile*16+c][col mt*16+q*4+r]
  float4* ob4 = (float4*)(out + (size_t)(tile * 16 + c) * MM) + q;
#pragma unroll
  for (int g = 0; g < 4; g++) {
    uint4 nb0[4], nb1[4];
    if (g < 3) {
#pragma unroll
      for (int j = 0; j < 4; j++) {
        nb0[j] = cenb[(((g + 1) * 4 + j) * 16 + c) * 8 + q];
        nb1[j] = cenb[(((g + 1) * 4 + j) * 16 + c) * 8 + 4 + q];
      }
    }
#pragma unroll
    for (int j = 0; j < 4; j++) {
      int mt = g * 4 + j;
      U16x8 b0, b1; b0.u = pb0[j]; b1.u = pb1[j];
      f32x4 dacc = {0, 0, 0, 0};
      dacc = __builtin_amdgcn_mfma_f32_16x16x32_bf16(b0.v, a0.v, dacc, 0, 0, 0);
      dacc = __builtin_amdgcn_mfma_f32_16x16x32_bf16(b1.v, a1.v, dacc, 0, 0, 0);
      UH2 p0, p1; p0.u = ep[mt].x; p1.u = ep[mt].y;
      float4 v;
      v.x = dacc[0] * ((float)p0.h[0] * sc);
      v.y = dacc[1] * ((float)p0.h[1] * sc);
      v.z = dacc[2] * ((float)p1.h[0] * sc);
      v.w = dacc[3] * ((float)p1.h[1] * sc);
      ob4[mt * 4] = v;   // imm offset mt*64B, one base per lane
    }
    if (g < 3) {
#pragma unroll
      for (int j = 0; j < 4; j++) { pb0[j] = nb0[j]; pb1[j] = nb1[j]; }
    }
  }
}

extern "C" void kernel_launch(void* const* d_in, const int* in_sizes, int n_in,
                              void* d_out, int out_size, void* d_ws, size_t ws_size,
                              hipStream_t stream) {
  const int* clu_coords = (const int*)d_in[0];
  const int* cen_coords = (const int*)d_in[1];
  const float* clu_feats = (const float*)d_in[2];
  const float* cen_feats = (const float*)d_in[3];
  const float* conf      = (const float*)d_in[4];
  const float* W         = (const float*)d_in[5];
  const float* bvec      = (const float*)d_in[6];
  float* out = (float*)d_out;

  char* ws = (char*)d_ws;
  unsigned short* cen_ws = (unsigned short*)ws;              // 32768 B
  unsigned short* wt_ws  = (unsigned short*)(ws + 32768);    // 16384 B
  float4* cmeta_ws       = (float4*)(ws + 32768 + 16384);    // 4096 B

  prep_kernel<<<17, 256, 0, stream>>>(cen_coords, cen_feats, conf, W, bvec,
                                      cen_ws, wt_ws, cmeta_ws);
  main_kernel<<<(NTILES + 3) / 4, 256, 0, stream>>>(
      (const int4*)clu_coords, clu_feats, bvec, cen_ws, wt_ws, cmeta_ws, out);
}

// Round 15
// 183.653 us; speedup vs baseline: 1.0789x; 1.0789x over previous
//
#include <hip/hip_runtime.h>
#include <stdint.h>

// InstanceHead on MI355X — f32/int32 inputs, f32 OUTPUT buffer.
// N=100000, M=256, B=8, L=128, D=64.
// R20: R18's cen->LDS epilogue (unique feature of the best-timed kernel,
// dur 183.7) with R18's pathology removed.  R18 put ONE barrier at the top
// covering cmeta + the 32KB cen staging: the compiler's vmcnt(0) drain
// before s_barrier forced st+ff+wbv ALL complete before ANY compute, in
// lockstep (profiled main 86us vs R14's 70).  R20:
//   - barrier #1 at top covers ONLY cmeta (1 load; waves arrive together)
//   - ff/wbv issued first, cen staging loads after; commit unpinned (no
//     adjacent barrier -> plain vmcnt wait, no cross-wave coupling)
//   - barrier #2 just before the epilogue: each wave has ~3000cy of
//     independent work behind it, zero outstanding vmem -> free drain;
//     cen_s4 visible for the LDS epilogue
//   - tail waves clamp tile to 6249 and run fully (duplicate stores of
//     identical bytes = benign) -> no divergence at barriers
// Keeps: swapped GEMM1 (b64 transposed LDS writes, 2-shuffle norm, float4
// bias), swizzled cen LDS (col4 ^= m&7 both sides, HW-verified R18),
// two-pass softmax, ep packed f16x2 in regs, transposed GEMM2 (row c,
// dwordx4 imm-offset stores), geometric batch fold (x+=4096*b), cmeta LDS,
// __launch_bounds__(256,3).

#define NN 100000
#define MM 256
#define LL 128
#define DD 64
#define NTILES (NN / 16)  // 6250, exact

typedef float f32x4 __attribute__((ext_vector_type(4)));
typedef __bf16 bf16x8 __attribute__((ext_vector_type(8)));
typedef __fp16 fp16x2 __attribute__((ext_vector_type(2)));

union U16x8 { uint4 u; bf16x8 v; unsigned short s[8]; };
union UH2 { unsigned int u; fp16x2 h; };

static __device__ __forceinline__ unsigned short f2bf(float f) {
  union { float f; unsigned int i; } t; t.f = f;
  unsigned int x = t.i;
  x += 0x7fffu + ((x >> 16) & 1u);  // round-to-nearest-even
  return (unsigned short)(x >> 16);
}

static __device__ __forceinline__ unsigned int pk_bf16(float lo, float hi) {
  unsigned int r;
  asm("v_cvt_pk_bf16_f32 %0, %1, %2" : "=v"(r) : "v"(lo), "v"(hi));
  return r;
}

// ---------------- prep: cen (bf16), W^T (bf16), centroid meta ----------------
__global__ __launch_bounds__(256) void prep_kernel(
    const int* __restrict__ cen_coords,
    const float* __restrict__ cen_feats,
    const float* __restrict__ conf,
    const float* __restrict__ W,
    const float* __restrict__ bvec,
    unsigned short* __restrict__ cen_ws,   // [256][64] bf16
    unsigned short* __restrict__ wt_ws,    // [64][128] bf16 (W transposed)
    float4* __restrict__ cmeta_ws)         // [256] {x+4096*batch, y, z, 0}
{
  int tid = threadIdx.x;
  if (blockIdx.x < 16) {
    int m = blockIdx.x * 16 + (tid >> 4);
    int c = tid & 15;
    float a0 = 0.f, a1 = 0.f, a2 = 0.f, a3 = 0.f;
    for (int l = 0; l < LL; l++) {
      float f = cen_feats[m * LL + l];
      const float* wr = W + l * DD + c;
      a0 += f * wr[0];  a1 += f * wr[16];
      a2 += f * wr[32]; a3 += f * wr[48];
    }
    float cf = conf[m];
    cen_ws[m * DD + c +  0] = f2bf(cf * (a0 + bvec[c +  0]));
    cen_ws[m * DD + c + 16] = f2bf(cf * (a1 + bvec[c + 16]));
    cen_ws[m * DD + c + 32] = f2bf(cf * (a2 + bvec[c + 32]));
    cen_ws[m * DD + c + 48] = f2bf(cf * (a3 + bvec[c + 48]));
  } else {
    for (int i = tid; i < LL * DD; i += 256) {
      int l = i >> 6, d = i & 63;
      wt_ws[d * LL + l] = f2bf(W[l * DD + d]);
    }
    {
      int4 cc = ((const int4*)cen_coords)[tid];  // {batch, x, y, z}
      float4 f;
      f.x = (float)cc.y + 4096.0f * (float)cc.x;  // batch folded into x
      f.y = (float)cc.z;
      f.z = (float)cc.w;
      f.w = 0.0f;
      cmeta_ws[tid] = f;
    }
  }
}

// ---------------- main: fused, 1 wave/tile, late-barrier cen-LDS ----------------
__global__ __launch_bounds__(256, 3) void main_kernel(
    const int4* __restrict__ clu_coords4,
    const float* __restrict__ feats,
    const float* __restrict__ bvec,
    const unsigned short* __restrict__ cen_ws,
    const unsigned short* __restrict__ wt_ws,
    const float4* __restrict__ cmeta,
    float* __restrict__ out)
{
  __shared__ __align__(16) uint4 cen_s4[2048];                // 32 KB, swizzled
  __shared__ __align__(16) float4 cmeta_s[MM];                // 4 KB
  __shared__ __align__(16) unsigned short clu_s[4][16 * 72];  // 9 KB, wave-private

  int tid = threadIdx.x;
  int wave = tid >> 6, lane = tid & 63;
  int q = lane >> 4, c = lane & 15, s = c & 7;
  int tile = blockIdx.x * 4 + wave;
  if (tile >= NTILES) tile = NTILES - 1;  // tail: duplicate-compute (benign dup stores)

  // ---- barrier #1: cmeta only (waves arrive together; drain = 1 load)
  cmeta_s[tid] = cmeta[tid];
  __syncthreads();

  // ---- per-wave bursts: feats (8x dwordx4) + W frags (16x dwordx4) FIRST
  const float4* fb = (const float4*)(feats + (size_t)(tile * 16 + c) * LL);
  float4 ff[8];
#pragma unroll
  for (int ks = 0; ks < 4; ks++) {
    ff[2 * ks]     = fb[ks * 8 + q * 2];
    ff[2 * ks + 1] = fb[ks * 8 + q * 2 + 1];
  }
  const uint4* wb = (const uint4*)wt_ws;
  uint4 wbv[16];
#pragma unroll
  for (int ks = 0; ks < 4; ks++)
#pragma unroll
    for (int nt = 0; nt < 4; nt++)
      wbv[ks * 4 + nt] = wb[(nt * 16 + c) * 16 + ks * 4 + q];

  // ---- cen staging loads (pre-swizzled gather: LDS[m][col4] = g[m][col4^ (m&7)])
  const uint4* cg = (const uint4*)cen_ws;
  uint4 st[8];
#pragma unroll
  for (int i = 0; i < 8; i++) {
    int fl = tid + i * 256;                       // LDS slot
    int g = (fl & ~7) | ((fl ^ (fl >> 3)) & 7);   // source col4 ^ (m&7)
    st[i] = cg[g];
  }

  // ---- row meta + bias
  int4 rm = clu_coords4[tile * 16 + c];            // one row per lane
  float rx = (float)rm.y + 4096.0f * (float)rm.x;  // batch folded, exact
  float ry = (float)rm.z;
  float rz = (float)rm.w;
  const float4* bv4 = (const float4*)bvec;
  float4 bb[4];
#pragma unroll
  for (int nt = 0; nt < 4; nt++) bb[nt] = bv4[nt * 4 + q];

  // ---- GEMM1 SWAPPED: acc[nt] lane (c,q) reg r = clu[i=c][d=nt*16+q*4+r]
  f32x4 acc[4] = {{0,0,0,0},{0,0,0,0},{0,0,0,0},{0,0,0,0}};
#pragma unroll
  for (int ks = 0; ks < 4; ks++) {
    float4 f0 = ff[2 * ks], f1 = ff[2 * ks + 1];
    U16x8 a;
    a.v[0] = (__bf16)f0.x; a.v[1] = (__bf16)f0.y; a.v[2] = (__bf16)f0.z; a.v[3] = (__bf16)f0.w;
    a.v[4] = (__bf16)f1.x; a.v[5] = (__bf16)f1.y; a.v[6] = (__bf16)f1.z; a.v[7] = (__bf16)f1.w;
#pragma unroll
    for (int nt = 0; nt < 4; nt++) {
      U16x8 b; b.u = wbv[ks * 4 + nt];
      acc[nt] = __builtin_amdgcn_mfma_f32_16x16x32_bf16(b.v, a.v, acc[nt], 0, 0, 0);  // SWAPPED
    }
  }

  // ---- commit cen staging to LDS (no adjacent barrier -> plain vmcnt wait)
#pragma unroll
  for (int i = 0; i < 8; i++) cen_s4[tid + i * 256] = st[i];

#pragma unroll
  for (int nt = 0; nt < 4; nt++) {
    acc[nt][0] += bb[nt][0]; acc[nt][1] += bb[nt][1];
    acc[nt][2] += bb[nt][2]; acc[nt][3] += bb[nt][3];
  }
  // ---- row norm: per-lane partial + 2 shuffles over q-lanes
  float ns = 0.f;
#pragma unroll
  for (int nt = 0; nt < 4; nt++)
#pragma unroll
    for (int r = 0; r < 4; r++) ns += acc[nt][r] * acc[nt][r];
  ns += __shfl_xor(ns, 16);
  ns += __shfl_xor(ns, 32);
  float inv_nrm = 1.0f / fmaxf(sqrtf(ns), 1e-12f);

  // ---- normalized clu -> LDS: 4x ds_write_b64 (contiguous d per nt)
#pragma unroll
  for (int nt = 0; nt < 4; nt++) {
    uint2 w;
    w.x = pk_bf16(acc[nt][0] * inv_nrm, acc[nt][1] * inv_nrm);
    w.y = pk_bf16(acc[nt][2] * inv_nrm, acc[nt][3] * inv_nrm);
    *(uint2*)&clu_s[wave][c * 72 + nt * 16 + q * 4] = w;  // 8B-aligned
  }

  // wave-private LDS transpose: DS pipe is in-order per wave, no barrier
  __builtin_amdgcn_sched_barrier(0);

  // ---- clu frags (B-operand of the swapped GEMM2): row c, k-slice q
  const uint4* cb = (const uint4*)(clu_s[wave]);
  U16x8 a0, a1;
  a0.u = cb[c * 9 + q];       // k = q*8 .. q*8+7
  a1.u = cb[c * 9 + 4 + q];   // k = 32+q*8 ..

  // ---- pass 1: d^2 min for (row c, cols mt*16+q*4+r) — per-lane scalar
  float d2m = 1e30f;
#pragma unroll
  for (int mt = 0; mt < 16; mt++) {
#pragma unroll
    for (int r = 0; r < 4; r++) {
      float4 cm = cmeta_s[mt * 16 + q * 4 + r];
      float dx = rx - cm.x, dy = ry - cm.y, dz = rz - cm.z;
      d2m = fminf(d2m, dx * dx + dy * dy + dz * dz);
    }
  }
  d2m = fminf(d2m, __shfl_xor(d2m, 16));
  d2m = fminf(d2m, __shfl_xor(d2m, 32));
  float dmv = fmaxf(sqrtf(d2m), 0.1f);  // softmax reference (row min dist)

  // ---- pass 2: e = exp(dmin - d) once; pack f16x2 along r; row sum
  uint2 ep[16];
  float rsum = 0.f;
#pragma unroll
  for (int mt = 0; mt < 16; mt++) {
    float e[4];
#pragma unroll
    for (int r = 0; r < 4; r++) {
      float4 cm = cmeta_s[mt * 16 + q * 4 + r];
      float dx = rx - cm.x, dy = ry - cm.y, dz = rz - cm.z;
      float d = fmaxf(sqrtf(dx * dx + dy * dy + dz * dz), 0.1f);
      e[r] = __expf(dmv - d);  // <= 1; cross-batch -> exact 0
      rsum += e[r];
    }
    UH2 p0, p1;
    p0.h = __builtin_amdgcn_cvt_pkrtz(e[0], e[1]);
    p1.h = __builtin_amdgcn_cvt_pkrtz(e[2], e[3]);
    ep[mt].x = p0.u;
    ep[mt].y = p1.u;
  }
  rsum += __shfl_xor(rsum, 16);
  rsum += __shfl_xor(rsum, 32);
  // d2m >= 4e6 <=> no same-batch centroid -> exact-zero row
  float sc = (d2m < 4.0e6f) ? 1.0f / rsum : 0.f;

  // ---- barrier #2: cen_s4 ready (each wave arrives with zero outstanding
  //      vmem and ~3000cy of independent work behind it -> cheap drain)
  __syncthreads();

  // ---- epilogue: swapped GEMM2; cen A-frags from swizzled LDS
  //      (slot = (mt*16+c)*8 + (col4 ^ (c&7)), col4 = q / q+4)
  float4* ob4 = (float4*)(out + (size_t)(tile * 16 + c) * MM) + q;
  int i0 = c * 8 + (q ^ s);
  int i1 = c * 8 + ((q + 4) ^ s);
#pragma unroll
  for (int mt = 0; mt < 16; mt++) {
    U16x8 b0, b1;
    b0.u = cen_s4[mt * 128 + i0];
    b1.u = cen_s4[mt * 128 + i1];
    f32x4 dacc = {0, 0, 0, 0};
    dacc = __builtin_amdgcn_mfma_f32_16x16x32_bf16(b0.v, a0.v, dacc, 0, 0, 0);
    dacc = __builtin_amdgcn_mfma_f32_16x16x32_bf16(b1.v, a1.v, dacc, 0, 0, 0);
    UH2 p0, p1; p0.u = ep[mt].x; p1.u = ep[mt].y;
    float4 v;
    v.x = dacc[0] * ((float)p0.h[0] * sc);
    v.y = dacc[1] * ((float)p0.h[1] * sc);
    v.z = dacc[2] * ((float)p1.h[0] * sc);
    v.w = dacc[3] * ((float)p1.h[1] * sc);
    ob4[mt * 4] = v;   // imm offset mt*64B, one base per lane
  }
}

extern "C" void kernel_launch(void* const* d_in, const int* in_sizes, int n_in,
                              void* d_out, int out_size, void* d_ws, size_t ws_size,
                              hipStream_t stream) {
  const int* clu_coords = (const int*)d_in[0];
  const int* cen_coords = (const int*)d_in[1];
  const float* clu_feats = (const float*)d_in[2];
  const float* cen_feats = (const float*)d_in[3];
  const float* conf      = (const float*)d_in[4];
  const float* W         = (const float*)d_in[5];
  const float* bvec      = (const float*)d_in[6];
  float* out = (float*)d_out;

  char* ws = (char*)d_ws;
  unsigned short* cen_ws = (unsigned short*)ws;              // 32768 B
  unsigned short* wt_ws  = (unsigned short*)(ws + 32768);    // 16384 B
  float4* cmeta_ws       = (float4*)(ws + 32768 + 16384);    // 4096 B

  prep_kernel<<<17, 256, 0, stream>>>(cen_coords, cen_feats, conf, W, bvec,
                                      cen_ws, wt_ws, cmeta_ws);
  main_kernel<<<(NTILES + 3) / 4, 256, 0, stream>>>(
      (const int4*)clu_coords, clu_feats, bvec, cen_ws, wt_ws, cmeta_ws, out);
}